// Round 12
// baseline (301.929 us; speedup 1.0000x reference)
//
#include <hip/hip_runtime.h>
#include <cstddef>

// HVAE tree decoder, fused single kernel. Round 12: 16 waves (1024 thr).
// Grid = 256 (1 block/CU), 64 rows/block; wave w owns nt-tile (w&7) of N=128
// x row-half (w>>3) — TWO 16-row tiles per wave (r11: 8 waves x four tiles).
// Why: r3-r11 occupancy law: waves/SIMD = 512/(arch+acc regs). r11's 4-rt
// waves need ~108+48 -> 2/SIMD; 2-rt waves need ~75+24 <= 128 -> 4/SIMD.
// Same block tile, same total MFMA, same LDS — but double the waves hiding
// LDS/L2 latency + barrier drain (the ~40% idle in r11's profile). Weight
// frags now loaded by 2 waves each (2x L2 weight traffic; L2 has headroom).
// Pred stays on waves 0-3 = one per SIMD: pred-phase wall-clock unchanged.
// Kept from r10/r11 (all green): k-major gru, ua-before-barrier in type-2,
// skip-max softmax, direct fragment-layout nontemporal logits store, leaf
// barrier elision, 5-op tanh, fast repack, biases pre-summed in LDS.
// No inline asm (cvt_pk NaN'd r1/r2); scalar f2bf; rcp activations.
// SH/PSLD multiples of 8 shorts (ds_read_b128 alignment).

#define BB   16384
#define HH   128
#define OO   32
#define ROWS 64

typedef __attribute__((ext_vector_type(8))) short bf8;
typedef __attribute__((ext_vector_type(4))) float f4;

#define MFMA(a, b, c) __builtin_amdgcn_mfma_f32_16x16x32_bf16(a, b, c, 0, 0, 0)

// packed-weight offsets in ws (shorts)
#define PW_Z2H 0         // [64x128]  -> 8192
#define PW_AWI 8192      // [96x128]  -> 12288
#define PW_AWH 20480     // [384x128] -> 49152
#define PW_FWI 69632     // [96x128]  -> 12288
#define PW_FWH 81920     // [384x128] -> 49152
#define PW_UA  131072    // [128x128] -> 16384
#define PW_UF  147456    // [128x128] -> 16384
#define PW_H2O 163840    // [128x32]  -> 4096
#define PW_END 167936

#define SH   136   // LDS h row stride (shorts): 272B rows (16B-aligned)
#define PSLD 40    // LDS probs row stride (shorts): 80B rows (16B-aligned)

// bias LDS layout (floats)
#define BA_RZ  0      // abi[0..255]+abh[0..255] (r at +0, z at +128)
#define BA_BH2 256    // abh gate2
#define BA_BI2 384    // abi gate2
#define BF_RZ  512
#define BF_BH2 768
#define BF_BI2 896
#define BU     1024   // uab+ufb
#define BZ2H   1152
#define BH2O   1280   // 32
#define BIAS_N 1312

__device__ __forceinline__ short f2bf(float f) {
  union { float f; unsigned u; } v; v.f = f;
  unsigned r = v.u + 0x7fff + ((v.u >> 16) & 1);   // RNE
  return (short)(r >> 16);
}
__device__ __forceinline__ float bf2f(short h) {
  union { unsigned u; float f; } v;
  v.u = ((unsigned)(unsigned short)h) << 16;
  return v.f;
}
__device__ __forceinline__ float rcp_(float x) { return __builtin_amdgcn_rcpf(x); }
__device__ __forceinline__ float sigmoidf_(float x) { return rcp_(1.0f + __expf(-x)); }
// tanh = 1 - 2/(e^{2x}+1): x>=44 -> e=inf -> rcp=0 -> 1; x<<0 -> e=0 -> -1.
__device__ __forceinline__ float tanhf_(float x) {
  const float e = __expf(2.0f * x);
  return 1.0f - 2.0f * rcp_(e + 1.0f);
}

// ---------------- repack: fp32 [K][N] -> B-frag-major bf16 -------------------
// 8 elems per thread: thread t covers frag-slot t (16B write), j=0..7 in-lane.
template <int K, int N>
__device__ __forceinline__ void repack8(const float* __restrict__ W,
                                        short* __restrict__ P, int t) {
  const int KC = K / 32;
  const int lane = t & 63, rest = t >> 6;
  const int kc = rest % KC, nt = rest / KC;
  const int k0 = kc * 32 + ((lane >> 4) << 3);
  const int n = nt * 16 + (lane & 15);
  union { short s[8]; bf8 v; } u;
#pragma unroll
  for (int j = 0; j < 8; ++j) u.s[j] = f2bf(W[(size_t)(k0 + j) * N + n]);
  *(bf8*)(P + (size_t)t * 8) = u.v;
}

__global__ __launch_bounds__(256) void k_repack(
    const float* __restrict__ z2hw, const float* __restrict__ awi,
    const float* __restrict__ awh, const float* __restrict__ fwi,
    const float* __restrict__ fwh, const float* __restrict__ uaw,
    const float* __restrict__ ufw, const float* __restrict__ h2ow,
    short* __restrict__ ws) {
  const int t = blockIdx.x * 256 + threadIdx.x;
  if (t < 1024)        repack8<64, 128>(z2hw, ws + PW_Z2H, t);
  else if (t < 2560)   repack8<96, 128>(awi, ws + PW_AWI, t - 1024);
  else if (t < 8704)   repack8<384, 128>(awh, ws + PW_AWH, t - 2560);
  else if (t < 10240)  repack8<96, 128>(fwi, ws + PW_FWI, t - 8704);
  else if (t < 16384)  repack8<384, 128>(fwh, ws + PW_FWH, t - 10240);
  else if (t < 18432)  repack8<128, 128>(uaw, ws + PW_UA, t - 16384);
  else if (t < 20480)  repack8<128, 128>(ufw, ws + PW_UF, t - 18432);
  else if (t < 20992)  repack8<128, 32>(h2ow, ws + PW_H2O, t - 20480);
}

// ---------------- slice helpers (wave: nt tile wnt, rows rb..rb+31) ----------
__device__ __forceinline__ void store_slice(const f4* hv, short* dst, int lane,
                                            int wnt, int rb) {
  const int l15 = lane & 15, q = lane >> 4;
#pragma unroll
  for (int rt = 0; rt < 2; ++rt)
#pragma unroll
    for (int j = 0; j < 4; ++j)
      dst[(rb + rt * 16 + q * 4 + j) * SH + wnt * 16 + l15] = f2bf(hv[rt][j]);
}

// GRU slice, k-major (r11 green structure, 2 row-tiles): per 32-wide k-slice
// load 2 h-frags + 3 gate weights, 6 MFMAs into persistent t2/rr/rz.
__device__ __forceinline__ void gru_slice(const short* xs, const short* hsrc,
                                          const short* wiP, const short* whP,
                                          const float* brz, const float* bh2v,
                                          const float* bi2v,
                                          int lane, int wnt, int rb, f4* hv) {
  const int l15 = lane & 15, q = lane >> 4;
  const int col = wnt * 16 + l15;
  const bf8* wi = (const bf8*)wiP;
  const bf8* wh = (const bf8*)whP;
  f4 t2[2], rr[2], rz[2];
  {
    const float bn = bh2v[col], br = brz[col], bz = brz[128 + col];
#pragma unroll
    for (int rt = 0; rt < 2; ++rt) {
      t2[rt] = (f4){bn, bn, bn, bn};
      rr[rt] = (f4){br, br, br, br};
      rz[rt] = (f4){bz, bz, bz, bz};
    }
  }
#pragma unroll
  for (int c = 0; c < 4; ++c) {
    const bf8 Wr = wh[(wnt * 12 + 0 + c) * 64 + lane];
    const bf8 Wz = wh[(wnt * 12 + 4 + c) * 64 + lane];
    const bf8 Wn = wh[(wnt * 12 + 8 + c) * 64 + lane];
    bf8 ah[2];
#pragma unroll
    for (int rt = 0; rt < 2; ++rt)
      ah[rt] = *(const bf8*)(hsrc + (rb + rt * 16 + l15) * SH + c * 32 + q * 8);
#pragma unroll
    for (int rt = 0; rt < 2; ++rt) {
      rr[rt] = MFMA(ah[rt], Wr, rr[rt]);
      rz[rt] = MFMA(ah[rt], Wz, rz[rt]);
      t2[rt] = MFMA(ah[rt], Wn, t2[rt]);
    }
  }
  // x-part + epilogue
  const bf8 Wxr = wi[(wnt * 3 + 0) * 64 + lane];
  const bf8 Wxz = wi[(wnt * 3 + 1) * 64 + lane];
  const bf8 Wxn = wi[(wnt * 3 + 2) * 64 + lane];
  bf8 ax[2];
#pragma unroll
  for (int rt = 0; rt < 2; ++rt)
    ax[rt] = *(const bf8*)(xs + (rb + rt * 16 + l15) * PSLD + q * 8);
#pragma unroll
  for (int rt = 0; rt < 2; ++rt) rr[rt] = MFMA(ax[rt], Wxr, rr[rt]);
  const float b2 = bi2v[col];
#pragma unroll
  for (int rt = 0; rt < 2; ++rt)
#pragma unroll
    for (int j = 0; j < 4; ++j)
      t2[rt][j] = t2[rt][j] * sigmoidf_(rr[rt][j]) + b2;  // r*(h@wh2+bh2)+bi2
#pragma unroll
  for (int rt = 0; rt < 2; ++rt) t2[rt] = MFMA(ax[rt], Wxn, t2[rt]);
#pragma unroll
  for (int rt = 0; rt < 2; ++rt) rz[rt] = MFMA(ax[rt], Wxz, rz[rt]);
  // h' = n + z*(h - n)
#pragma unroll
  for (int rt = 0; rt < 2; ++rt)
#pragma unroll
    for (int j = 0; j < 4; ++j) {
      const float hc = bf2f(hsrc[(rb + rt * 16 + q * 4 + j) * SH + col]);
      const float zz = sigmoidf_(rz[rt][j]);
      const float nn = tanhf_(t2[rt][j]);
      hv[rt][j] = nn + zz * (hc - nn);
    }
}

// preorder schedule, depth 4: type 0=root, 1=left child (gru_a), 2=right child
__device__ const unsigned char d_TYPE[31] =
    {0,1,1,1,1,2,2,1,2,2,1,1,2,2,1,2,2,1,1,1,2,2,1,2,2,1,1,2,2,1,2};
__device__ const unsigned char d_LVL[31] =
    {0,1,2,3,4,4,3,4,4,2,3,4,4,3,4,4,1,2,3,4,4,3,4,4,2,3,4,4,3,4,4};

// ---------------- the fused tree kernel -------------------------------------
__global__ __launch_bounds__(1024, 1) void k_tree(
    const float* __restrict__ zf, const short* __restrict__ pw,
    const float* __restrict__ z2hb, const float* __restrict__ abi,
    const float* __restrict__ abh, const float* __restrict__ fbi,
    const float* __restrict__ fbh, const float* __restrict__ uab,
    const float* __restrict__ ufb, const float* __restrict__ h2ob,
    float* __restrict__ out) {
  __shared__ __align__(16) short hstk[5 * ROWS * SH];   // 87040 B
  __shared__ __align__(16) short hfb[ROWS * SH];        // 17408 B (type-2 only)
  __shared__ __align__(16) short pstk[5 * ROWS * PSLD]; // 25600 B
  __shared__ float bias[BIAS_N];                        // 5248 B => 135296 B
  const int lane = threadIdx.x & 63;
  const int w = threadIdx.x >> 6;        // 16 waves
  const int wnt = w & 7;                 // nt tile (16 cols)
  const int rb = (w >> 3) * 32;          // row-half base (0 or 32)
  const int l15 = lane & 15, q = lane >> 4;
  const int col = wnt * 16 + l15;
  const int r0 = blockIdx.x * ROWS;

  // bias preload: pre-summed where the algorithm always sums them
  for (int t = threadIdx.x; t < BIAS_N; t += 1024) {
    float v;
    if (t < 256)       v = abi[t] + abh[t];
    else if (t < 384)  v = abh[t];           // abh gate2
    else if (t < 512)  v = abi[t - 128];     // abi gate2
    else if (t < 768)  v = fbi[t - 512] + fbh[t - 512];
    else if (t < 896)  v = fbh[t - 512];
    else if (t < 1024) v = fbi[t - 640];
    else if (t < 1152) v = uab[t - 1024] + ufb[t - 1024];
    else if (t < 1280) v = z2hb[t - 1152];
    else               v = h2ob[t - 1280];
    bias[t] = v;
  }
  __syncthreads();

  // root: h_in[0] = z @ z2h + b  (z read as f32, scalar f2bf in-register)
  {
    const bf8* wz = (const bf8*)(pw + PW_Z2H);
    const bf8 W0 = wz[(wnt * 2 + 0) * 64 + lane];
    const bf8 W1 = wz[(wnt * 2 + 1) * 64 + lane];
    const float b = bias[BZ2H + col];
    f4 hv[2];
#pragma unroll
    for (int rt = 0; rt < 2; ++rt) {
      const float* zr = zf + (size_t)(r0 + rb + rt * 16 + l15) * 64 + q * 8;
      union { short s[8]; bf8 v; } A0, A1;
      {
        const f4 x0 = *(const f4*)zr, x1 = *(const f4*)(zr + 4);
#pragma unroll
        for (int j = 0; j < 4; ++j) { A0.s[j] = f2bf(x0[j]); A0.s[4 + j] = f2bf(x1[j]); }
        const f4 y0 = *(const f4*)(zr + 32), y1 = *(const f4*)(zr + 36);
#pragma unroll
        for (int j = 0; j < 4; ++j) { A1.s[j] = f2bf(y0[j]); A1.s[4 + j] = f2bf(y1[j]); }
      }
      f4 acc = (f4){b, b, b, b};
      acc = MFMA(A0.v, W0, acc);
      acc = MFMA(A1.v, W1, acc);
      hv[rt] = acc;
    }
    store_slice(hv, hstk, lane, wnt, rb);
  }
  __syncthreads();

#pragma unroll 1
  for (int i = 0; i < 31; ++i) {
    const int t = d_TYPE[i];
    const int L = d_LVL[i];
    short* hcur = hstk + L * ROWS * SH;
    short* pcur = pstk + L * ROWS * PSLD;

    if (t == 2) {
      // h_f = gru_f(probs_sib, h_sib)
      f4 hf[2];
      gru_slice(pcur, hcur, pw + PW_FWI, pw + PW_FWH,
                bias + BF_RZ, bias + BF_BH2, bias + BF_BI2, lane, wnt, rb, hf);
      store_slice(hf, hfb, lane, wnt, rb);
      // h2 = tanh(h_f@uf + h_par@ua + b): the ua half needs only pre-barrier
      // data — run it between the hf store and the barrier (overlaps drain).
      const short* hpar = hstk + (L - 1) * ROWS * SH;
      const bf8* ua = (const bf8*)(pw + PW_UA);
      f4 hv[2];
      {
        const float b = bias[BU + col];
#pragma unroll
        for (int rt = 0; rt < 2; ++rt) hv[rt] = (f4){b, b, b, b};
      }
#pragma unroll
      for (int c = 0; c < 4; ++c) {
        const bf8 Wa = ua[(wnt * 4 + c) * 64 + lane];
#pragma unroll
        for (int rt = 0; rt < 2; ++rt) {
          const bf8 ap = *(const bf8*)(hpar + (rb + rt * 16 + l15) * SH + c * 32 + q * 8);
          hv[rt] = MFMA(ap, Wa, hv[rt]);
        }
      }
      __syncthreads();
      const bf8* uf = (const bf8*)(pw + PW_UF);
#pragma unroll
      for (int c = 0; c < 4; ++c) {
        const bf8 Wf = uf[(wnt * 4 + c) * 64 + lane];
#pragma unroll
        for (int rt = 0; rt < 2; ++rt) {
          const bf8 af = *(const bf8*)(hfb + (rb + rt * 16 + l15) * SH + c * 32 + q * 8);
          hv[rt] = MFMA(af, Wf, hv[rt]);
        }
      }
#pragma unroll
      for (int rt = 0; rt < 2; ++rt)
#pragma unroll
        for (int j = 0; j < 4; ++j) hv[rt][j] = tanhf_(hv[rt][j]);
      store_slice(hv, hcur, lane, wnt, rb);
      __syncthreads();
    }

    // pred + softmax: waves 0..3 (one per SIMD), one 16-row tile each.
    // Skip-max softmax (|logits| <~ 10 << 88); logits straight to global
    // (fragment layout: pa+pb of a row = one 128B line); probs bf16 -> pstk.
    if (w < 4) {
      bf8 a[4];
#pragma unroll
      for (int c = 0; c < 4; ++c)
        a[c] = *(const bf8*)(hcur + (w * 16 + l15) * SH + c * 32 + q * 8);
      const bf8* bw = (const bf8*)(pw + PW_H2O);
      bf8 W[8];
#pragma unroll
      for (int f = 0; f < 8; ++f) W[f] = bw[f * 64 + lane];
      const float b0 = bias[BH2O + l15];
      const float b1 = bias[BH2O + 16 + l15];
      f4 pa = (f4){b0, b0, b0, b0};
      f4 pb = (f4){b1, b1, b1, b1};
#pragma unroll
      for (int c = 0; c < 4; ++c) {
        pa = MFMA(a[c], W[c], pa);
        pb = MFMA(a[c], W[4 + c], pb);
      }
      float* ob = out + ((size_t)i * BB + r0 + w * 16 + q * 4) * OO + l15;
#pragma unroll
      for (int j = 0; j < 4; ++j) {
        __builtin_nontemporal_store(pa[j], ob + j * OO);
        __builtin_nontemporal_store(pb[j], ob + j * OO + 16);
      }
#pragma unroll
      for (int j = 0; j < 4; ++j) {
        const float e0 = __expf(pa[j]), e1 = __expf(pb[j]);
        float ss = e0 + e1;
#pragma unroll
        for (int s = 1; s < 16; s <<= 1) ss += __shfl_xor(ss, s);
        const float inv = rcp_(ss);
        short* pr = pcur + (w * 16 + q * 4 + j) * PSLD;
        pr[l15] = f2bf(e0 * inv);
        pr[16 + l15] = f2bf(e1 * inv);
      }
    }
    __syncthreads();

    // non-leaf: h_in[L+1] = gru_a(probs, h_in[L]); leaves skip the barrier too
    if (L < 4) {
      f4 hv[2];
      gru_slice(pcur, hcur, pw + PW_AWI, pw + PW_AWH,
                bias + BA_RZ, bias + BA_BH2, bias + BA_BI2, lane, wnt, rb, hv);
      store_slice(hv, hstk + (L + 1) * ROWS * SH, lane, wnt, rb);
      __syncthreads();
    }
  }
}

// ---------------- host ------------------------------------------------------
extern "C" void kernel_launch(void* const* d_in, const int* in_sizes, int n_in,
                              void* d_out, int out_size, void* d_ws, size_t ws_size,
                              hipStream_t stream) {
  const float* z    = (const float*)d_in[0];
  const float* z2hw = (const float*)d_in[1];
  const float* z2hb = (const float*)d_in[2];
  const float* h2ow = (const float*)d_in[3];
  const float* h2ob = (const float*)d_in[4];
  const float* awi  = (const float*)d_in[5];
  const float* abi  = (const float*)d_in[6];
  const float* awh  = (const float*)d_in[7];
  const float* abh  = (const float*)d_in[8];
  const float* fwi  = (const float*)d_in[9];
  const float* fbi  = (const float*)d_in[10];
  const float* fwh  = (const float*)d_in[11];
  const float* fbh  = (const float*)d_in[12];
  const float* uaw  = (const float*)d_in[13];
  const float* uab  = (const float*)d_in[14];
  const float* ufw  = (const float*)d_in[15];
  const float* ufb  = (const float*)d_in[16];

  float* out = (float*)d_out;
  short* ws  = (short*)d_ws;

  k_repack<<<82, 256, 0, stream>>>(
      z2hw, awi, awh, fwi, fwh, uaw, ufw, h2ow, ws);

  k_tree<<<BB / ROWS, 1024, 0, stream>>>(
      z, ws, z2hb, abi, abh, fbi, fbh, uab, ufb, h2ob, out);
}